// Round 2
// baseline (257.588 us; speedup 1.0000x reference)
//
#include <hip/hip_runtime.h>
#include <math.h>

// Problem constants (static shapes from setup_inputs; all arrays are float32)
#define B_  2
#define T_  8
#define R_  128
#define NP_ 32768
#define F_  5
#define S_  32   // num_sample

// One wave (64 lanes) per (b,t,r) row: ordered predicate scan over Np points,
// select first S_ in-radius points (ascending index, matching stable top_k on
// a 0/1 mask), copy 5 f32 features, zero-fill remaining slots.
__global__ __launch_bounds__(256) void voxel_sampler_kernel(
    const float* __restrict__ points,   // [B,T,Np,5]
    const float* __restrict__ rois,     // [B,T,R,9]
    float* __restrict__ out)            // [B,R,T*S,5]
{
    const int wave = blockIdx.x * (blockDim.x >> 6) + (threadIdx.x >> 6);
    const int lane = threadIdx.x & 63;
    if (wave >= B_ * T_ * R_) return;

    // r fastest -> the 4 waves of a block share the same (b,t) point slab (L1/L2 locality)
    const int r  = wave % R_;
    const int bt = wave / R_;          // b*T + t
    const int t  = bt % T_;
    const int b  = bt / T_;

    // ---- per-row constants, f32 op-for-op vs numpy f32 reference ----
    const float* roi = rois + ((size_t)bt * R_ + r) * 9;
    const float cx = roi[0];
    const float cy = roi[1];
    const float hx = roi[3] * 0.5f;
    const float hy = roi[4] * 0.5f;
    const float vx = roi[7];
    const float vy = roi[8];

    const float speed  = sqrtf(vx * vx + vy * vy);          // f32 ops, IEEE sqrt
    const float base_g = 1.05f * (1.0f + speed);            // GAMMA*(1+speed)
    const float expo   = (float)t / 5.0f;                   // t_idx/5.0 in f32
    // f64 pow rounded to f32 ~= correctly-rounded powf (matches glibc powf)
    const float gamma  = fminf((float)pow((double)base_g, (double)expo), 2.5f);
    const float radius = sqrtf(hx * hx + hy * hy) * gamma;

    const float* pb = points + (size_t)bt * NP_ * F_;
    float* orow = out + ((((size_t)b * R_ + r) * T_ + t) * S_) * F_;

    // ---- ordered scan: first S_ in-radius indices ----
    int sel = 0;  // wave-uniform count of hits so far
    for (int base = 0; base < NP_; base += 64) {
        const int i = base + lane;                       // NP_ % 64 == 0
        const float* p = pb + (size_t)i * F_;
        const float px = p[0];
        const float py = p[1];
        const float qx = px - cx;
        const float qy = py - cy;
        const float dis = sqrtf(qx * qx + qy * qy);      // compare sqrt form, like ref
        const bool pred = (dis <= radius);

        const unsigned long long m = __ballot(pred);
        if (m) {
            if (pred) {
                const int rank = __popcll(m & ((1ull << lane) - 1ull));
                const int slot = sel + rank;
                if (slot < S_) {
                    float* o = orow + (size_t)slot * F_;
                    o[0] = px; o[1] = py; o[2] = p[2]; o[3] = p[3]; o[4] = p[4];
                }
            }
            sel += __popcll(m);
            if (sel >= S_) break;   // wave-uniform early exit
        }
    }

    // ---- zero-fill unfilled slots (harness poisons d_out) ----
    const int filled = sel < S_ ? sel : S_;
    const int rem = (S_ - filled) * F_;
    float* ztail = orow + (size_t)filled * F_;
    for (int j = lane; j < rem; j += 64) ztail[j] = 0.0f;
}

extern "C" void kernel_launch(void* const* d_in, const int* in_sizes, int n_in,
                              void* d_out, int out_size, void* d_ws, size_t ws_size,
                              hipStream_t stream) {
    const float* points = (const float*)d_in[0];
    const float* rois   = (const float*)d_in[1];
    // d_in[2] = num_sample (int, ==32) — baked into S_ (static-shape harness)
    float* out = (float*)d_out;

    const int nrows = B_ * T_ * R_;          // 2048 waves
    const int block = 256;                   // 4 waves/block
    const int grid  = nrows / (block / 64);  // 512 blocks
    voxel_sampler_kernel<<<grid, block, 0, stream>>>(points, rois, out);
}

// Round 3
// 130.818 us; speedup vs baseline: 1.9691x; 1.9691x over previous
//
#include <hip/hip_runtime.h>
#include <math.h>

// Problem constants (static shapes from setup_inputs; all arrays are float32)
#define B_   2
#define T_   8
#define R_   128
#define NP_  32768
#define F_   5
#define S_   32          // num_sample
#define SEG_ 2048        // points per phase-1 segment
#define NSEG (NP_ / SEG_) // 16
#define NBT  (B_ * T_)    // 16
#define NROW (NBT * R_)   // 2048

// ---------------- kernel 1: AoS -> SoA xy transpose ----------------
__global__ __launch_bounds__(256) void xy_transpose(
    const float* __restrict__ points,  // [bt, Np, 5]
    float2* __restrict__ xy)           // [bt, Np]
{
    const int i = blockIdx.x * blockDim.x + threadIdx.x;  // over NBT*NP_
    if (i < NBT * NP_) {
        const float* p = points + (size_t)i * F_;
        xy[i] = make_float2(p[0], p[1]);
    }
}

// ---------------- kernel 2: segmented ordered hit collection ----------------
// block = 256 = 4 waves; each wave: one (bt, seg, roi). All 4 waves of a block
// share the same 16 KB xy segment (L1-resident reuse).
__global__ __launch_bounds__(256) void phase1_collect(
    const float2* __restrict__ xy,       // [bt, Np]
    const float* __restrict__ rois,      // [bt, R, 9]
    int* __restrict__ counts,            // [row, NSEG]   (row = bt*R + r)
    unsigned short* __restrict__ hitidx) // [row, NSEG, S_]
{
    const int blk = blockIdx.x;                 // (bt*NSEG + seg)*(R_/4) + rg
    const int rg  = blk % (R_ / 4);
    const int bs  = blk / (R_ / 4);
    const int seg = bs % NSEG;
    const int bt  = bs / NSEG;
    const int w    = threadIdx.x >> 6;
    const int lane = threadIdx.x & 63;
    const int r    = rg * 4 + w;
    const int t    = bt % T_;
    const int row  = bt * R_ + r;

    // per-row radius, f32 op-for-op vs numpy f32 reference
    const float* roi = rois + ((size_t)bt * R_ + r) * 9;
    const float cx = roi[0], cy = roi[1];
    const float hx = roi[3] * 0.5f, hy = roi[4] * 0.5f;
    const float vx = roi[7], vy = roi[8];
    const float speed  = sqrtf(vx * vx + vy * vy);
    const float base_g = 1.05f * (1.0f + speed);
    const float expo   = (float)t / 5.0f;
    const float gamma  = fminf((float)pow((double)base_g, (double)expo), 2.5f);
    const float radius = sqrtf(hx * hx + hy * hy) * gamma;

    const float2* x = xy + (size_t)bt * NP_ + (size_t)seg * SEG_;
    unsigned short* hrow = hitidx + ((size_t)row * NSEG + seg) * S_;

    int sel = 0;
    for (int base = 0; base < SEG_; base += 64) {
        const float2 pt = x[base + lane];
        const float qx = pt.x - cx;
        const float qy = pt.y - cy;
        const bool pred = (sqrtf(qx * qx + qy * qy) <= radius);
        const unsigned long long m = __ballot(pred);
        if (m) {
            if (pred) {
                const int slot = sel + __popcll(m & ((1ull << lane) - 1ull));
                if (slot < S_)
                    hrow[slot] = (unsigned short)(seg * SEG_ + base + lane);
            }
            sel += __popcll(m);
            if (sel >= S_) break;  // capped below; later base ranks already >= S_
        }
    }
    if (lane == 0) counts[(size_t)row * NSEG + seg] = (sel < S_) ? sel : S_;
}

// ---------------- kernel 3: prefix + gather + zero-fill ----------------
// one wave per row; block = 4 rows
__global__ __launch_bounds__(256) void phase2_gather(
    const float* __restrict__ points,          // [bt, Np, 5]
    const int* __restrict__ counts,            // [row, NSEG]
    const unsigned short* __restrict__ hitidx, // [row, NSEG, S_]
    float* __restrict__ out)                   // [B, R, T*S, 5]
{
    const int wave = blockIdx.x * 4 + (threadIdx.x >> 6);
    const int lane = threadIdx.x & 63;
    if (wave >= NROW) return;
    const int row = wave;
    const int r  = row % R_;
    const int bt = row / R_;
    const int t  = bt % T_;
    const int b  = bt / T_;

    // slot j = lane (j < S_): locate owning segment via running prefix
    int seg = -1, local = 0, acc = 0;
    const int j = lane;
    for (int s = 0; s < NSEG; ++s) {
        const int cs = counts[(size_t)row * NSEG + s];  // wave-uniform load
        if (seg < 0 && j < acc + cs) { seg = s; local = j - acc; }
        acc += cs;
    }
    const int total = (acc < S_) ? acc : S_;

    float* orow = out + ((((size_t)b * R_ + r) * T_ + t) * S_) * F_;
    if (lane < S_) {
        float* o = orow + (size_t)lane * F_;
        if (lane < total) {
            const int pi = hitidx[((size_t)row * NSEG + seg) * S_ + local];
            const float* p = points + ((size_t)bt * NP_ + pi) * F_;
            o[0] = p[0]; o[1] = p[1]; o[2] = p[2]; o[3] = p[3]; o[4] = p[4];
        } else {
            o[0] = 0.0f; o[1] = 0.0f; o[2] = 0.0f; o[3] = 0.0f; o[4] = 0.0f;
        }
    }
}

extern "C" void kernel_launch(void* const* d_in, const int* in_sizes, int n_in,
                              void* d_out, int out_size, void* d_ws, size_t ws_size,
                              hipStream_t stream) {
    const float* points = (const float*)d_in[0];
    const float* rois   = (const float*)d_in[1];
    float* out = (float*)d_out;

    // workspace layout (6.3 MB total)
    char* ws = (char*)d_ws;
    float2* xy             = (float2*)ws;                            // 4,194,304 B
    int* counts            = (int*)(ws + (size_t)NBT * NP_ * 8);     //   131,072 B
    unsigned short* hitidx = (unsigned short*)(ws + (size_t)NBT * NP_ * 8
                                                  + (size_t)NROW * NSEG * 4); // 2,097,152 B

    // 1) transpose xy to SoA (coalesced phase-1 reads)
    xy_transpose<<<(NBT * NP_ + 255) / 256, 256, 0, stream>>>(points, xy);

    // 2) segmented ordered hit collection: 16 bt x 16 seg x 32 roi-groups
    phase1_collect<<<NBT * NSEG * (R_ / 4), 256, 0, stream>>>(xy, rois, counts, hitidx);

    // 3) prefix + gather + zero-fill: 2048 rows, 4 rows/block
    phase2_gather<<<NROW / 4, 256, 0, stream>>>(points, counts, hitidx, out);
}

// Round 4
// 109.173 us; speedup vs baseline: 2.3595x; 1.1983x over previous
//
#include <hip/hip_runtime.h>
#include <math.h>

// Problem constants (static shapes from setup_inputs; all arrays are float32)
#define B_   2
#define T_   8
#define R_   128
#define NP_  32768
#define F_   5
#define S_   32           // num_sample
#define SEG_ 2048         // points per phase-1 segment
#define NSEG (NP_ / SEG_) // 16
#define NBT  (B_ * T_)    // 16
#define NROW (NBT * R_)   // 2048

// ---------- kernel 1: vectorized AoS->SoA xy transpose + per-row constant prep ----------
// thread j transposes points 4j..4j+3 (5 float4 loads -> 2 float4 stores).
// threads j < NROW additionally compute per-row (cx, cy, T) where
// T = max{ x : sqrtf(x) <= radius }  — makes the phase-1 predicate sqrt-free
// yet bit-identical (sqrtf monotone + correctly rounded).
__global__ __launch_bounds__(256) void xy_transpose_prep(
    const float* __restrict__ points,  // [bt, Np, 5]
    const float* __restrict__ rois,    // [bt, R, 9]
    float2* __restrict__ xy,           // [bt, Np]
    float4* __restrict__ rowc)         // [row] = {cx, cy, T, 0}
{
    const int j = blockIdx.x * blockDim.x + threadIdx.x;
    if (j < NBT * NP_ / 4) {
        const float4* src = (const float4*)points + (size_t)j * 5;
        const float4 a = src[0], b = src[1], c = src[2], d = src[3], e = src[4];
        float4* dst = (float4*)xy + (size_t)j * 2;
        dst[0] = make_float4(a.x, a.y, b.y, b.z);   // pts 4j, 4j+1
        dst[1] = make_float4(c.z, c.w, d.w, e.x);   // pts 4j+2, 4j+3
    }
    if (j < NROW) {
        const int row = j;                 // row = bt*R + r
        const int bt  = row / R_;
        const int t   = bt % T_;
        const float* roi = rois + (size_t)row * 9;
        const float cx = roi[0], cy = roi[1];
        const float hx = roi[3] * 0.5f, hy = roi[4] * 0.5f;
        const float vx = roi[7], vy = roi[8];
        const float speed  = sqrtf(vx * vx + vy * vy);
        const float base_g = 1.05f * (1.0f + speed);
        const float expo   = (float)t / 5.0f;
        const float gamma  = fminf((float)pow((double)base_g, (double)expo), 2.5f);
        const float radius = sqrtf(hx * hx + hy * hy) * gamma;   // same as passing rounds
        // ulp-walk: largest float T with sqrtf(T) <= radius (radius >= 0.5, normal)
        unsigned ut = __float_as_uint(radius * radius);
        while (sqrtf(__uint_as_float(ut)) > radius) --ut;
        while (sqrtf(__uint_as_float(ut + 1u)) <= radius) ++ut;
        rowc[row] = make_float4(cx, cy, __uint_as_float(ut), 0.0f);
    }
}

// ---------- kernel 2: segmented ordered hit collection (sqrt-free) ----------
// block = 256 = 4 waves; wave = one (bt, seg, roi); 4 rois share a 16 KB L1 segment.
__global__ __launch_bounds__(256) void phase1_collect(
    const float2* __restrict__ xy,       // [bt, Np]
    const float4* __restrict__ rowc,     // [row]
    int* __restrict__ counts,            // [row, NSEG]
    unsigned short* __restrict__ hitidx) // [row, NSEG, S_]
{
    const int blk = blockIdx.x;                 // (bt*NSEG + seg)*(R_/4) + rg
    const int rg  = blk % (R_ / 4);
    const int bs  = blk / (R_ / 4);
    const int seg = bs % NSEG;
    const int bt  = bs / NSEG;
    const int w    = threadIdx.x >> 6;
    const int lane = threadIdx.x & 63;
    const int row  = bt * R_ + rg * 4 + w;

    const float4 rc = rowc[row];
    const float cx = rc.x, cy = rc.y, T = rc.z;

    const float2* x = xy + (size_t)bt * NP_ + (size_t)seg * SEG_;
    unsigned short* hrow = hitidx + ((size_t)row * NSEG + seg) * S_;

    int sel = 0;
    #pragma unroll 4
    for (int base = 0; base < SEG_; base += 64) {
        const float2 pt = x[base + lane];
        const float qx = pt.x - cx;
        const float qy = pt.y - cy;
        const float d2 = qx * qx + qy * qy;      // same expr/contraction as before
        const bool pred = (d2 <= T);             // == (sqrtf(d2) <= radius), exactly
        const unsigned long long m = __ballot(pred);
        if (pred) {
            const int slot = sel + __popcll(m & ((1ull << lane) - 1ull));
            if (slot < S_)
                hrow[slot] = (unsigned short)(seg * SEG_ + base + lane);
        }
        sel += __popcll(m);                      // scalar s_bcnt1_b64
    }
    if (lane == 0) counts[(size_t)row * NSEG + seg] = (sel < S_) ? sel : S_;
}

// ---------- kernel 3: prefix + gather + zero-fill ----------
// one thread per (row, slot): 65536 threads, no cross-lane ops.
__global__ __launch_bounds__(256) void phase2_gather(
    const float* __restrict__ points,          // [bt, Np, 5]
    const int* __restrict__ counts,            // [row, NSEG]
    const unsigned short* __restrict__ hitidx, // [row, NSEG, S_]
    float* __restrict__ out)                   // [B, R, T*S, 5]
{
    const int tid  = blockIdx.x * blockDim.x + threadIdx.x;
    const int slot = tid & (S_ - 1);
    const int row  = tid >> 5;                 // S_ == 32
    if (row >= NROW) return;
    const int r  = row % R_;
    const int bt = row / R_;
    const int t  = bt % T_;
    const int b  = bt / T_;

    const int4* cp = (const int4*)(counts + (size_t)row * NSEG);
    const int4 q0 = cp[0], q1 = cp[1], q2 = cp[2], q3 = cp[3];
    const int cs[16] = {q0.x,q0.y,q0.z,q0.w, q1.x,q1.y,q1.z,q1.w,
                        q2.x,q2.y,q2.z,q2.w, q3.x,q3.y,q3.z,q3.w};
    int seg = -1, local = 0, acc = 0;
    #pragma unroll
    for (int s = 0; s < NSEG; ++s) {
        const int na = acc + cs[s];
        if (seg < 0 && slot < na) { seg = s; local = slot - acc; }
        acc = na;
    }
    const int total = (acc < S_) ? acc : S_;

    float* o = out + (((((size_t)b * R_ + r) * T_ + t) * S_) + slot) * F_;
    if (slot < total) {
        const int pi = hitidx[((size_t)row * NSEG + seg) * S_ + local];
        const float* p = points + ((size_t)bt * NP_ + pi) * F_;
        o[0] = p[0]; o[1] = p[1]; o[2] = p[2]; o[3] = p[3]; o[4] = p[4];
    } else {
        o[0] = 0.0f; o[1] = 0.0f; o[2] = 0.0f; o[3] = 0.0f; o[4] = 0.0f;
    }
}

extern "C" void kernel_launch(void* const* d_in, const int* in_sizes, int n_in,
                              void* d_out, int out_size, void* d_ws, size_t ws_size,
                              hipStream_t stream) {
    const float* points = (const float*)d_in[0];
    const float* rois   = (const float*)d_in[1];
    float* out = (float*)d_out;

    // workspace layout (~6.4 MB)
    char* ws = (char*)d_ws;
    float2* xy             = (float2*)ws;                                   // 4,194,304 B
    int* counts            = (int*)(ws + 4194304);                          //   131,072 B
    unsigned short* hitidx = (unsigned short*)(ws + 4194304 + 131072);      // 2,097,152 B
    float4* rowc           = (float4*)(ws + 4194304 + 131072 + 2097152);    //    32,768 B

    // 1) vectorized transpose + per-row constants (fused)
    xy_transpose_prep<<<(NBT * NP_ / 4 + 255) / 256, 256, 0, stream>>>(points, rois, xy, rowc);

    // 2) segmented ordered hit collection: 16 bt x 16 seg x 32 roi-groups
    phase1_collect<<<NBT * NSEG * (R_ / 4), 256, 0, stream>>>(xy, rowc, counts, hitidx);

    // 3) prefix + gather + zero-fill: one thread per (row, slot)
    phase2_gather<<<(NROW * S_) / 256, 256, 0, stream>>>(points, counts, hitidx, out);
}

// Round 5
// 84.410 us; speedup vs baseline: 3.0516x; 1.2934x over previous
//
#include <hip/hip_runtime.h>
#include <math.h>

// Problem constants (static shapes from setup_inputs; all arrays are float32)
#define B_   2
#define T_   8
#define R_   128
#define NP_  32768
#define F_   5
#define S_   32           // num_sample
#define SEG_ 2048         // points per phase-1 segment
#define NSEG (NP_ / SEG_) // 16
#define NBT  (B_ * T_)    // 16
#define NROW (NBT * R_)   // 2048
#define RPB  8            // rois per block (2 per wave)

__device__ __forceinline__ int mbcnt64(unsigned long long m) {
    return __builtin_amdgcn_mbcnt_hi((unsigned)(m >> 32),
           __builtin_amdgcn_mbcnt_lo((unsigned)m, 0u));
}

// ---------- kernel 1: vectorized AoS->SoA xy transpose + per-row constant prep ----------
// T = max{ x : sqrtf(x) <= radius } makes the phase-1 predicate sqrt-free yet
// bit-identical (sqrtf monotone + correctly rounded).
__global__ __launch_bounds__(256) void xy_transpose_prep(
    const float* __restrict__ points,  // [bt, Np, 5]
    const float* __restrict__ rois,    // [bt, R, 9]
    float2* __restrict__ xy,           // [bt, Np]
    float4* __restrict__ rowc)         // [row] = {cx, cy, T, 0}
{
    const int j = blockIdx.x * blockDim.x + threadIdx.x;
    if (j < NBT * NP_ / 4) {
        const float4* src = (const float4*)points + (size_t)j * 5;
        const float4 a = src[0], b = src[1], c = src[2], d = src[3], e = src[4];
        float4* dst = (float4*)xy + (size_t)j * 2;
        dst[0] = make_float4(a.x, a.y, b.y, b.z);   // pts 4j, 4j+1
        dst[1] = make_float4(c.z, c.w, d.w, e.x);   // pts 4j+2, 4j+3
    }
    if (j < NROW) {
        const int row = j;                 // row = bt*R + r
        const int bt  = row / R_;
        const int t   = bt % T_;
        const float* roi = rois + (size_t)row * 9;
        const float cx = roi[0], cy = roi[1];
        const float hx = roi[3] * 0.5f, hy = roi[4] * 0.5f;
        const float vx = roi[7], vy = roi[8];
        const float speed  = sqrtf(vx * vx + vy * vy);
        const float base_g = 1.05f * (1.0f + speed);
        const float expo   = (float)t / 5.0f;
        const float gamma  = fminf((float)pow((double)base_g, (double)expo), 2.5f);
        const float radius = sqrtf(hx * hx + hy * hy) * gamma;   // same as passing rounds
        // ulp-walk: largest float T with sqrtf(T) <= radius
        unsigned ut = __float_as_uint(radius * radius);
        while (sqrtf(__uint_as_float(ut)) > radius) --ut;
        while (sqrtf(__uint_as_float(ut + 1u)) <= radius) ++ut;
        rowc[row] = make_float4(cx, cy, __uint_as_float(ut), 0.0f);
    }
}

// ---------- kernel 2: LDS-staged segmented ordered hit collection ----------
// block = 256 (4 waves) on one (bt, seg): stage 16 KB xy segment to LDS once,
// each wave scans it for 2 rois, 2 points per lane per ds_read_b128.
__global__ __launch_bounds__(256) void phase1_collect(
    const float2* __restrict__ xy,       // [bt, Np]
    const float4* __restrict__ rowc,     // [row]
    int* __restrict__ counts,            // [row, NSEG]
    unsigned short* __restrict__ hitidx) // [row, NSEG, S_]
{
    __shared__ float4 tile[SEG_ / 2];    // 16 KB: 1024 point-pairs

    const int blk = blockIdx.x;                 // (bt*NSEG + seg)*(R_/RPB) + rg
    const int rg  = blk % (R_ / RPB);
    const int bs  = blk / (R_ / RPB);
    const int seg = bs % NSEG;
    const int bt  = bs / NSEG;
    const int w    = threadIdx.x >> 6;
    const int lane = threadIdx.x & 63;

    // cooperative stage: 1024 float4 / 256 threads = 4 each (coalesced)
    const float4* src = (const float4*)(xy + (size_t)bt * NP_ + (size_t)seg * SEG_);
    #pragma unroll
    for (int i = 0; i < 4; ++i)
        tile[i * 256 + threadIdx.x] = src[i * 256 + threadIdx.x];
    __syncthreads();

    const int row0 = bt * R_ + rg * RPB + w * 2;
    const int row1 = row0 + 1;
    const float4 rc0 = rowc[row0], rc1 = rowc[row1];
    unsigned short* h0 = hitidx + ((size_t)row0 * NSEG + seg) * S_;
    unsigned short* h1 = hitidx + ((size_t)row1 * NSEG + seg) * S_;

    int sel0 = 0, sel1 = 0;
    const int ibase = seg * SEG_;
    #pragma unroll 2
    for (int it = 0; it < SEG_ / 128; ++it) {   // 16 iterations
        const float4 q = tile[it * 64 + lane];  // points idx0, idx0+1
        const int idx0 = ibase + (it * 64 + lane) * 2;

        // strict numpy rounding: mul, mul, add separately rounded (no fma)
        // roi 0
        {
            const float ax = __fsub_rn(q.x, rc0.x), ay = __fsub_rn(q.y, rc0.y);
            const float bx = __fsub_rn(q.z, rc0.x), by = __fsub_rn(q.w, rc0.y);
            const float d2a = __fadd_rn(__fmul_rn(ax, ax), __fmul_rn(ay, ay));
            const float d2b = __fadd_rn(__fmul_rn(bx, bx), __fmul_rn(by, by));
            const bool p0 = (d2a <= rc0.z), p1 = (d2b <= rc0.z);
            const unsigned long long m0 = __ballot(p0), m1 = __ballot(p1);
            if (m0 | m1) {
                const int base = sel0 + mbcnt64(m0) + mbcnt64(m1);
                if (p0 && base < S_) h0[base] = (unsigned short)idx0;
                if (p1) { const int s = base + (p0 ? 1 : 0);
                          if (s < S_) h0[s] = (unsigned short)(idx0 + 1); }
                sel0 += __popcll(m0) + __popcll(m1);
            }
        }
        // roi 1 (re-uses the same LDS read)
        {
            const float ax = __fsub_rn(q.x, rc1.x), ay = __fsub_rn(q.y, rc1.y);
            const float bx = __fsub_rn(q.z, rc1.x), by = __fsub_rn(q.w, rc1.y);
            const float d2a = __fadd_rn(__fmul_rn(ax, ax), __fmul_rn(ay, ay));
            const float d2b = __fadd_rn(__fmul_rn(bx, bx), __fmul_rn(by, by));
            const bool p0 = (d2a <= rc1.z), p1 = (d2b <= rc1.z);
            const unsigned long long m0 = __ballot(p0), m1 = __ballot(p1);
            if (m0 | m1) {
                const int base = sel1 + mbcnt64(m0) + mbcnt64(m1);
                if (p0 && base < S_) h1[base] = (unsigned short)idx0;
                if (p1) { const int s = base + (p0 ? 1 : 0);
                          if (s < S_) h1[s] = (unsigned short)(idx0 + 1); }
                sel1 += __popcll(m0) + __popcll(m1);
            }
        }
    }
    if (lane == 0) {
        counts[(size_t)row0 * NSEG + seg] = (sel0 < S_) ? sel0 : S_;
        counts[(size_t)row1 * NSEG + seg] = (sel1 < S_) ? sel1 : S_;
    }
}

// ---------- kernel 3: prefix + gather + zero-fill ----------
// one thread per (row, slot): 65536 threads.
__global__ __launch_bounds__(256) void phase2_gather(
    const float* __restrict__ points,          // [bt, Np, 5]
    const int* __restrict__ counts,            // [row, NSEG]
    const unsigned short* __restrict__ hitidx, // [row, NSEG, S_]
    float* __restrict__ out)                   // [B, R, T*S, 5]
{
    const int tid  = blockIdx.x * blockDim.x + threadIdx.x;
    const int slot = tid & (S_ - 1);
    const int row  = tid >> 5;                 // S_ == 32
    if (row >= NROW) return;
    const int r  = row % R_;
    const int bt = row / R_;
    const int t  = bt % T_;
    const int b  = bt / T_;

    const int4* cp = (const int4*)(counts + (size_t)row * NSEG);
    const int4 q0 = cp[0], q1 = cp[1], q2 = cp[2], q3 = cp[3];
    const int cs[16] = {q0.x,q0.y,q0.z,q0.w, q1.x,q1.y,q1.z,q1.w,
                        q2.x,q2.y,q2.z,q2.w, q3.x,q3.y,q3.z,q3.w};
    int seg = -1, local = 0, acc = 0;
    #pragma unroll
    for (int s = 0; s < NSEG; ++s) {
        const int na = acc + cs[s];
        if (seg < 0 && slot < na) { seg = s; local = slot - acc; }
        acc = na;
    }
    const int total = (acc < S_) ? acc : S_;

    float* o = out + (((((size_t)b * R_ + r) * T_ + t) * S_) + slot) * F_;
    if (slot < total) {
        const int pi = hitidx[((size_t)row * NSEG + seg) * S_ + local];
        const float* p = points + ((size_t)bt * NP_ + pi) * F_;
        o[0] = p[0]; o[1] = p[1]; o[2] = p[2]; o[3] = p[3]; o[4] = p[4];
    } else {
        o[0] = 0.0f; o[1] = 0.0f; o[2] = 0.0f; o[3] = 0.0f; o[4] = 0.0f;
    }
}

extern "C" void kernel_launch(void* const* d_in, const int* in_sizes, int n_in,
                              void* d_out, int out_size, void* d_ws, size_t ws_size,
                              hipStream_t stream) {
    const float* points = (const float*)d_in[0];
    const float* rois   = (const float*)d_in[1];
    float* out = (float*)d_out;

    // workspace layout (~6.4 MB)
    char* ws = (char*)d_ws;
    float2* xy             = (float2*)ws;                                   // 4,194,304 B
    int* counts            = (int*)(ws + 4194304);                          //   131,072 B
    unsigned short* hitidx = (unsigned short*)(ws + 4194304 + 131072);      // 2,097,152 B
    float4* rowc           = (float4*)(ws + 4194304 + 131072 + 2097152);    //    32,768 B

    // 1) vectorized transpose + per-row constants (fused)
    xy_transpose_prep<<<(NBT * NP_ / 4 + 255) / 256, 256, 0, stream>>>(points, rois, xy, rowc);

    // 2) LDS-staged ordered hit collection: 16 bt x 16 seg x 16 roi-groups
    phase1_collect<<<NBT * NSEG * (R_ / RPB), 256, 0, stream>>>(xy, rowc, counts, hitidx);

    // 3) prefix + gather + zero-fill: one thread per (row, slot)
    phase2_gather<<<(NROW * S_) / 256, 256, 0, stream>>>(points, counts, hitidx, out);
}